// Round 6
// baseline (683.592 us; speedup 1.0000x reference)
//
#include <hip/hip_runtime.h>
#include <stdint.h>

#define T_DIM 512
#define B_DIM 128
#define I_DIM 1024
#define N_DIM 1024
#define NB (N_DIM * B_DIM)     // 131072
#define ROWB 4096              // combined W row bytes: I * (hi+lo f16)

#define DECAY 0.9f
#define THRESH 1.0f

typedef _Float16 f16;
typedef _Float16 f16x8 __attribute__((ext_vector_type(8)));
typedef float f32x4 __attribute__((ext_vector_type(4)));

struct B4 { float4 a, b, c, d; };

// -------------------------------------------------------------------------
// Split fp32 W -> combined f16 hi/lo layout: [row][kc=0..127][hl][8 f16].
// -------------------------------------------------------------------------
__global__ __launch_bounds__(256) void split_w_kernel(
    const float* __restrict__ W, f16* __restrict__ Ws)
{
    int gid = blockIdx.x * 256 + threadIdx.x;       // N*I/8 kchunks
    int kc  = gid & 127;
    int row = gid >> 7;
    const float* src = W + (size_t)row * I_DIM + kc * 8;
    f16* dst = Ws + (size_t)row * 2048 + kc * 16;
    float v[8];
    *(float4*)&v[0] = *(const float4*)src;
    *(float4*)&v[4] = *(const float4*)(src + 4);
    f16 hi[8], lo[8];
    #pragma unroll
    for (int j = 0; j < 8; ++j) {
        hi[j] = (f16)v[j];
        lo[j] = (f16)(v[j] - (float)hi[j]);
    }
    *(f16x8*)dst       = *(const f16x8*)hi;
    *(f16x8*)(dst + 8) = *(const f16x8*)lo;
}

// -------------------------------------------------------------------------
// GEMM via fp16-split 3xMFMA. 128n x 128b tile per block for one t,
// 4 waves (64x64 each), BK=32, 2 x 32KB LDS dbuf, 2 blocks/CU.
// A (W combined f16): global_load_lds, linear dest + inverse-XOR src.
// B (X fp32): reg-staged 2 tiles ahead -> convert to f16 hi/lo -> ds_write
//   (swizzled) into the NEXT buffer during the stage phase. Compute reads
//   pure f16 fragments; no convert on the critical path.
// Pipeline: s_barrier / stage A(kt+1), load B(kt+2) regs / vmcnt(8) /
//   convert+ds_write B(kt+1) / lgkmcnt(0) / s_barrier / 48 MFMA term-outer.
// vmcnt never drains to 0 mid-loop.
// -------------------------------------------------------------------------
__global__ __launch_bounds__(256, 2) void spk_gemm_kernel(
    const uint8_t* __restrict__ Wsb,   // combined W [N][kc][hl][8]
    const float* __restrict__ X,       // [B, T, I] fp32
    float* __restrict__ C,             // [tc, N, B] chunk
    int t0)
{
    __shared__ __align__(16) uint8_t lds[65536];   // 2 x (A 16K | B 16K)

    const int tid  = threadIdx.x;
    const int wave = tid >> 6, lane = tid & 63;
    const int wbase = wave << 6;

    // bijective chunked XCD swizzle: same-t blocks colocate on one XCD
    const int nwg = gridDim.x;
    const int q = nwg >> 3, r = nwg & 7;
    const int xcd = blockIdx.x & 7, idx = blockIdx.x >> 3;
    const int wg = (xcd < r ? xcd * (q + 1) : r * (q + 1) + (xcd - r) * q) + idx;
    const int n0 = (wg & 7) << 7;
    const int t  = t0 + (wg >> 3);

    // A staging sources: 4 granules (16B) per thread, inverse-XOR swizzled
    const uint8_t* srcA[4];
    #pragma unroll
    for (int c = 0; c < 4; ++c) {
        int G = c * 256 + tid;
        int rr = G >> 3, g = G & 7;
        srcA[c] = Wsb + (size_t)(n0 + rr) * ROWB + ((g ^ (rr & 7)) << 4);
    }

    // B staging: thread -> (row brr, half bhh); 16 floats per tile
    const int brr = tid >> 1, bhh = tid & 1;
    const uint8_t* bsrc = (const uint8_t*)X
        + ((size_t)brr * T_DIM + t) * (I_DIM * 4) + bhh * 64;
    // ds_write offsets (swizzled, content granule g stored at slot g^(row&7))
    const int dswH0 = 16384 + brr * 128 + (((bhh * 4 + 0) ^ (brr & 7)) << 4);
    const int dswL0 = 16384 + brr * 128 + (((bhh * 4 + 1) ^ (brr & 7)) << 4);
    const int dswH1 = 16384 + brr * 128 + (((bhh * 4 + 2) ^ (brr & 7)) << 4);
    const int dswL1 = 16384 + brr * 128 + (((bhh * 4 + 3) ^ (brr & 7)) << 4);

    // compute-side fragment offsets
    const int wr = ((wave >> 1) << 6);   // n-offset 0/64
    const int wc = ((wave & 1) << 6);    // b-offset 0/64
    const int l15 = lane & 15, kcg = lane >> 4, l7 = l15 & 7;
    int aoffH[4], aoffL[4], boffH[4], boffL[4];
    #pragma unroll
    for (int m = 0; m < 4; ++m) {
        int ra = wr + m * 16 + l15;
        aoffH[m] = ra * 128 + ((((kcg << 1) | 0) ^ l7) << 4);
        aoffL[m] = ra * 128 + ((((kcg << 1) | 1) ^ l7) << 4);
        int rb = wc + m * 16 + l15;
        boffH[m] = 16384 + rb * 128 + ((((kcg << 1) | 0) ^ l7) << 4);
        boffL[m] = 16384 + rb * 128 + ((((kcg << 1) | 1) ^ l7) << 4);
    }

    f32x4 acc[4][4];
    #pragma unroll
    for (int m = 0; m < 4; ++m)
        #pragma unroll
        for (int n = 0; n < 4; ++n) acc[m][n] = (f32x4){0.f, 0.f, 0.f, 0.f};

#define STAGE_A(KT1, QB) do {                                                 \
    _Pragma("unroll")                                                         \
    for (int c_ = 0; c_ < 4; ++c_)                                            \
        __builtin_amdgcn_global_load_lds(                                     \
            (const __attribute__((address_space(1))) uint8_t*)(srcA[c_] + (KT1) * 128), \
            (__attribute__((address_space(3))) uint8_t*)&lds[(QB) + (c_ * 256 + wbase) * 16], \
            16, 0, 0);                                                        \
} while (0)

#define LOAD_B(KT2, SLD) do {                                                 \
    const uint8_t* p_ = bsrc + (KT2) * 128;                                   \
    (SLD).a = *(const float4*)(p_);                                           \
    (SLD).b = *(const float4*)(p_ + 16);                                      \
    (SLD).c = *(const float4*)(p_ + 32);                                      \
    (SLD).d = *(const float4*)(p_ + 48);                                      \
} while (0)

#define CONV_WRITE(QB, SCV) do {                                              \
    float bf_[16];                                                            \
    *(float4*)&bf_[0]  = (SCV).a; *(float4*)&bf_[4]  = (SCV).b;               \
    *(float4*)&bf_[8]  = (SCV).c; *(float4*)&bf_[12] = (SCV).d;               \
    f16 h0_[8], l0_[8], h1_[8], l1_[8];                                       \
    _Pragma("unroll")                                                         \
    for (int j_ = 0; j_ < 8; ++j_) {                                          \
        f16 h_ = (f16)bf_[j_];                                                \
        h0_[j_] = h_; l0_[j_] = (f16)(bf_[j_] - (float)h_);                   \
    }                                                                         \
    _Pragma("unroll")                                                         \
    for (int j_ = 0; j_ < 8; ++j_) {                                          \
        f16 h_ = (f16)bf_[8 + j_];                                            \
        h1_[j_] = h_; l1_[j_] = (f16)(bf_[8 + j_] - (float)h_);               \
    }                                                                         \
    *(f16x8*)&lds[(QB) + dswH0] = *(f16x8*)h0_;                               \
    *(f16x8*)&lds[(QB) + dswL0] = *(f16x8*)l0_;                               \
    *(f16x8*)&lds[(QB) + dswH1] = *(f16x8*)h1_;                               \
    *(f16x8*)&lds[(QB) + dswL1] = *(f16x8*)l1_;                               \
} while (0)

#define COMPUTE(PB) do {                                                      \
    const uint8_t* bp_ = &lds[(PB)];                                          \
    f16x8 Ah_[4], Al_[4], Bh_[4], Bl_[4];                                     \
    _Pragma("unroll")                                                         \
    for (int m_ = 0; m_ < 4; ++m_) {                                          \
        Ah_[m_] = *(const f16x8*)&bp_[aoffH[m_]];                             \
        Al_[m_] = *(const f16x8*)&bp_[aoffL[m_]];                             \
    }                                                                         \
    _Pragma("unroll")                                                         \
    for (int n_ = 0; n_ < 4; ++n_) {                                          \
        Bh_[n_] = *(const f16x8*)&bp_[boffH[n_]];                             \
        Bl_[n_] = *(const f16x8*)&bp_[boffL[n_]];                             \
    }                                                                         \
    __builtin_amdgcn_s_setprio(1);                                            \
    _Pragma("unroll")                                                         \
    for (int m_ = 0; m_ < 4; ++m_)                                            \
        _Pragma("unroll")                                                     \
        for (int n_ = 0; n_ < 4; ++n_)                                        \
            acc[m_][n_] = __builtin_amdgcn_mfma_f32_16x16x32_f16(Ah_[m_], Bh_[n_], acc[m_][n_], 0, 0, 0); \
    _Pragma("unroll")                                                         \
    for (int m_ = 0; m_ < 4; ++m_)                                            \
        _Pragma("unroll")                                                     \
        for (int n_ = 0; n_ < 4; ++n_)                                        \
            acc[m_][n_] = __builtin_amdgcn_mfma_f32_16x16x32_f16(Ah_[m_], Bl_[n_], acc[m_][n_], 0, 0, 0); \
    _Pragma("unroll")                                                         \
    for (int m_ = 0; m_ < 4; ++m_)                                            \
        _Pragma("unroll")                                                     \
        for (int n_ = 0; n_ < 4; ++n_)                                        \
            acc[m_][n_] = __builtin_amdgcn_mfma_f32_16x16x32_f16(Al_[m_], Bh_[n_], acc[m_][n_], 0, 0, 0); \
    __builtin_amdgcn_s_setprio(0);                                            \
} while (0)

// One pipeline iteration. DOA/DOB/DOCV are compile-time 0/1; VMC a literal.
#define ITER(KT, SLD, SCV, VMC, DOA, DOB, DOCV) do {                          \
    __builtin_amdgcn_s_barrier();   /* all done reading buf q */              \
    {                                                                         \
        const int qb_ = ((((KT) & 1) ^ 1) << 15);                             \
        if (DOA) STAGE_A((KT) + 1, qb_);                                      \
        if (DOB) LOAD_B((KT) + 2, SLD);                                       \
        asm volatile("s_waitcnt vmcnt(" #VMC ")" ::: "memory");               \
        if (DOCV) {                                                           \
            CONV_WRITE(qb_, SCV);                                             \
            asm volatile("s_waitcnt lgkmcnt(0)" ::: "memory");                \
        }                                                                     \
        __builtin_amdgcn_s_barrier();  /* tile KT fully resident */           \
        __builtin_amdgcn_sched_barrier(0);                                    \
        COMPUTE(((KT) & 1) << 15);                                            \
    }                                                                         \
} while (0)

    B4 sB0, sB1;
    // prologue: B(0)->sB0, A(0)->buf0, B(1)->sB1, convert B(0)->buf0
    LOAD_B(0, sB0);
    STAGE_A(0, 0);
    LOAD_B(1, sB1);
    CONV_WRITE(0, sB0);
    asm volatile("s_waitcnt lgkmcnt(0)" ::: "memory");
    // invariant entering iter kt: outstanding = A(kt)x4 + B(kt+1)x4

    for (int kt = 0; kt < 30; kt += 2) {
        ITER(kt,     sB0, sB1, 8, 1, 1, 1);
        ITER(kt + 1, sB1, sB0, 8, 1, 1, 1);
    }
    ITER(30, sB0, sB1, 4, 1, 0, 1);   // stage A(31), convert B(31); no B load
    ITER(31, sB1, sB0, 0, 0, 0, 0);   // last compute

    // epilogue: C[t'][n][b]; C/D map col=lane&15, row=(lane>>4)*4+j
    float* cp = C + (size_t)(wg >> 3) * NB;
    const int rg = (lane >> 4) << 2;
    #pragma unroll
    for (int m = 0; m < 4; ++m) {
        int nrow = n0 + wr + m * 16 + rg;
        #pragma unroll
        for (int n = 0; n < 4; ++n) {
            int col = wc + n * 16 + l15;
            #pragma unroll
            for (int j = 0; j < 4; ++j)
                cp[(size_t)(nrow + j) * B_DIM + col] = acc[m][n][j];
        }
    }
}

// -------------------------------------------------------------------------
// Sequential LIF scan per (n,b); state carried across chunk launches.
// -------------------------------------------------------------------------
__global__ __launch_bounds__(256) void spk_scan_kernel(
    const float* __restrict__ cur,   // [tc, NB]
    float* __restrict__ mp_state,    // [NB]
    float* __restrict__ out,         // [NB]
    int tc, int first)
{
    const int nb = blockIdx.x * 256 + threadIdx.x;
    float mp, cnt;
    if (first) { mp = 0.0f; cnt = 0.0f; }
    else       { mp = mp_state[nb]; cnt = out[nb]; }

    const float* p = cur + nb;
    #pragma unroll 8
    for (int t = 0; t < tc; ++t) {
        float c = p[(size_t)t * NB];
        mp = __fadd_rn(__fmul_rn(DECAY, mp), c);
        if (mp >= THRESH) { cnt += 1.0f; mp = 0.0f; }
    }
    mp_state[nb] = mp;
    out[nb] = cnt;
}

extern "C" void kernel_launch(void* const* d_in, const int* in_sizes, int n_in,
                              void* d_out, int out_size, void* d_ws, size_t ws_size,
                              hipStream_t stream) {
    const float* x = (const float*)d_in[0];   // [B, T, I]
    const float* w = (const float*)d_in[1];   // [N, I]
    float* out = (float*)d_out;               // [N, B]

    uint8_t* ws = (uint8_t*)d_ws;
    float* mp  = (float*)ws;                                 // 512 KB
    f16*   Wsp = (f16*)(ws + 524288);                        // 4 MB combined W
    uint8_t* rest = ws + 524288 + 4194304;
    size_t rem = ws_size - 524288 - 4194304;

    // per-t footprint: cur only (512 KB)
    int Tc = (int)(rem / (size_t)(NB * 4));
    if (Tc > T_DIM) Tc = T_DIM;
    if (Tc < 1) Tc = 1;

    float* cur = (float*)rest;                               // Tc * 512 KB

    split_w_kernel<<<(N_DIM * I_DIM / 8) / 256, 256, 0, stream>>>(w, Wsp);

    int first = 1;
    for (int t0 = 0; t0 < T_DIM; ) {
        int tc = T_DIM - t0;
        if (tc > Tc) tc = Tc;

        spk_gemm_kernel<<<tc * 8, 256, 0, stream>>>((const uint8_t*)Wsp, x, cur, t0);
        spk_scan_kernel<<<NB / 256, 256, 0, stream>>>(cur, mp, out, tc, first);

        first = 0;
        t0 += tc;
    }
}

// Round 7
// 583.424 us; speedup vs baseline: 1.1717x; 1.1717x over previous
//
#include <hip/hip_runtime.h>
#include <stdint.h>

#define T_DIM 512
#define B_DIM 128
#define I_DIM 1024
#define N_DIM 1024
#define NB (N_DIM * B_DIM)     // 131072
#define ROWB 4096              // combined W row bytes: I * (hi+lo f16)

#define DECAY 0.9f
#define THRESH 1.0f

typedef _Float16 f16;
typedef _Float16 f16x8 __attribute__((ext_vector_type(8)));
typedef float f32x4 __attribute__((ext_vector_type(4)));

struct B4 { float4 a0, b0, a1, b1; };   // 2 units x 32B of raw fp32 X

// -------------------------------------------------------------------------
// Split fp32 W -> combined f16 hi/lo layout: [row][kc=0..127][hl][8 f16].
// -------------------------------------------------------------------------
__global__ __launch_bounds__(256) void split_w_kernel(
    const float* __restrict__ W, f16* __restrict__ Ws)
{
    int gid = blockIdx.x * 256 + threadIdx.x;       // N*I/8 kchunks
    int kc  = gid & 127;
    int row = gid >> 7;
    const float* src = W + (size_t)row * I_DIM + kc * 8;
    f16* dst = Ws + (size_t)row * 2048 + kc * 16;
    float v[8];
    *(float4*)&v[0] = *(const float4*)src;
    *(float4*)&v[4] = *(const float4*)(src + 4);
    f16 hi[8], lo[8];
    #pragma unroll
    for (int j = 0; j < 8; ++j) {
        hi[j] = (f16)v[j];
        lo[j] = (f16)(v[j] - (float)hi[j]);
    }
    *(f16x8*)dst       = *(const f16x8*)hi;
    *(f16x8*)(dst + 8) = *(const f16x8*)lo;
}

// -------------------------------------------------------------------------
// GEMM via fp16-split 3xMFMA. Round-3 geometry and compute path:
// 128n x 128b tile / block / t, 4 waves (64x64), BK=32, 2x32KB dbuf, 2 blk/CU.
// A (W combined): global_load_lds (linear dest, inverse-XOR src) — as round 3.
// B (X raw fp32): COALESCED per-thread reg loads (2 units x 32B contiguous),
//   converted to f16 hi/lo between the barriers (off the compute path),
//   ds_write_b128 into the same combined-B LDS layout round 3 read.
// Per iter kt: barrier / stage A(kt+1)+load B(kt+1) / vmcnt(8) /
//   conv+write B(kt) / lgkmcnt(0) / barrier / compute(kt).
// -------------------------------------------------------------------------
__global__ __launch_bounds__(256, 2) void spk_gemm_kernel(
    const uint8_t* __restrict__ Wsb,   // combined W [N][kc][hl][8]
    const float* __restrict__ X,       // [B, T, I] fp32
    float* __restrict__ C,             // [tc, N, B] chunk
    int t0)
{
    __shared__ __align__(16) uint8_t lds[65536];   // 2 x (A 16K | B 16K)

    const int tid  = threadIdx.x;
    const int wave = tid >> 6, lane = tid & 63;
    const int wbase = wave << 6;

    // bijective chunked XCD swizzle: same-t blocks colocate on one XCD
    const int nwg = gridDim.x;
    const int q = nwg >> 3, r = nwg & 7;
    const int xcd = blockIdx.x & 7, idx = blockIdx.x >> 3;
    const int wg = (xcd < r ? xcd * (q + 1) : r * (q + 1) + (xcd - r) * q) + idx;
    const int n0 = (wg & 7) << 7;
    const int t  = t0 + (wg >> 3);

    // A staging sources: 4 granules (16B) per thread, inverse-XOR swizzled
    const uint8_t* srcA[4];
    #pragma unroll
    for (int c = 0; c < 4; ++c) {
        int G = c * 256 + tid;
        int rr = G >> 3, g = G & 7;
        srcA[c] = Wsb + (size_t)(n0 + rr) * ROWB + ((g ^ (rr & 7)) << 4);
    }

    // B staging: unit u = (rb, j): 8 floats (32B) of row rb, kc-chunk j.
    // Thread owns units tid and 256+tid -> rows rb0 and rb0+64, same j0.
    const int rb0 = tid >> 2, j0 = tid & 3;
    const uint8_t* bsrc0 = (const uint8_t*)X
        + ((size_t)rb0 * T_DIM + t) * (I_DIM * 4) + j0 * 32;
    const uint8_t* bsrc1 = bsrc0 + (size_t)64 * T_DIM * (I_DIM * 4);
    // combined-B LDS dests: content granule gC stored at slot gC^(row&7)
    const int r7b = rb0 & 7;                        // (rb0+64)&7 == rb0&7
    const int dswHi0 = 16384 + rb0 * 128        + (((2 * j0    ) ^ r7b) << 4);
    const int dswLo0 = 16384 + rb0 * 128        + (((2 * j0 + 1) ^ r7b) << 4);
    const int dswHi1 = 16384 + (rb0 + 64) * 128 + (((2 * j0    ) ^ r7b) << 4);
    const int dswLo1 = 16384 + (rb0 + 64) * 128 + (((2 * j0 + 1) ^ r7b) << 4);

    // compute-side fragment offsets (identical to round 3)
    const int wr = ((wave >> 1) << 6);   // n-offset 0/64
    const int wc = ((wave & 1) << 6);    // b-offset 0/64
    const int l15 = lane & 15, kcg = lane >> 4, l7 = l15 & 7;
    int aoffH[4], aoffL[4], boffH[4], boffL[4];
    #pragma unroll
    for (int m = 0; m < 4; ++m) {
        int ra = wr + m * 16 + l15;
        aoffH[m] = ra * 128 + ((((kcg << 1) | 0) ^ l7) << 4);
        aoffL[m] = ra * 128 + ((((kcg << 1) | 1) ^ l7) << 4);
        int rb = wc + m * 16 + l15;
        boffH[m] = 16384 + rb * 128 + ((((kcg << 1) | 0) ^ l7) << 4);
        boffL[m] = 16384 + rb * 128 + ((((kcg << 1) | 1) ^ l7) << 4);
    }

    f32x4 acc[4][4];
    #pragma unroll
    for (int m = 0; m < 4; ++m)
        #pragma unroll
        for (int n = 0; n < 4; ++n) acc[m][n] = (f32x4){0.f, 0.f, 0.f, 0.f};

#define STAGE_A(KT1, QB) do {                                                 \
    _Pragma("unroll")                                                         \
    for (int c_ = 0; c_ < 4; ++c_)                                            \
        __builtin_amdgcn_global_load_lds(                                     \
            (const __attribute__((address_space(1))) uint8_t*)(srcA[c_] + (KT1) * 128), \
            (__attribute__((address_space(3))) uint8_t*)&lds[(QB) + (c_ * 256 + wbase) * 16], \
            16, 0, 0);                                                        \
} while (0)

#define LOAD_B(KT1, R) do {                                                   \
    const uint8_t* p0_ = bsrc0 + (KT1) * 128;                                 \
    const uint8_t* p1_ = bsrc1 + (KT1) * 128;                                 \
    (R).a0 = *(const float4*)(p0_);                                           \
    (R).b0 = *(const float4*)(p0_ + 16);                                      \
    (R).a1 = *(const float4*)(p1_);                                           \
    (R).b1 = *(const float4*)(p1_ + 16);                                      \
} while (0)

#define CONV_WRITE(QB, R) do {                                                \
    float f0_[8], f1_[8];                                                     \
    *(float4*)&f0_[0] = (R).a0; *(float4*)&f0_[4] = (R).b0;                   \
    *(float4*)&f1_[0] = (R).a1; *(float4*)&f1_[4] = (R).b1;                   \
    f16 h0_[8], l0_[8], h1_[8], l1_[8];                                       \
    _Pragma("unroll")                                                         \
    for (int j_ = 0; j_ < 8; ++j_) {                                          \
        f16 h_ = (f16)f0_[j_];                                                \
        h0_[j_] = h_; l0_[j_] = (f16)(f0_[j_] - (float)h_);                   \
    }                                                                         \
    _Pragma("unroll")                                                         \
    for (int j_ = 0; j_ < 8; ++j_) {                                          \
        f16 h_ = (f16)f1_[j_];                                                \
        h1_[j_] = h_; l1_[j_] = (f16)(f1_[j_] - (float)h_);                   \
    }                                                                         \
    *(f16x8*)&lds[(QB) + dswHi0] = *(f16x8*)h0_;                              \
    *(f16x8*)&lds[(QB) + dswLo0] = *(f16x8*)l0_;                              \
    *(f16x8*)&lds[(QB) + dswHi1] = *(f16x8*)h1_;                              \
    *(f16x8*)&lds[(QB) + dswLo1] = *(f16x8*)l1_;                              \
} while (0)

#define COMPUTE(PB) do {                                                      \
    const uint8_t* bp_ = &lds[(PB)];                                          \
    f16x8 Ah_[4], Al_[4], Bh_[4], Bl_[4];                                     \
    _Pragma("unroll")                                                         \
    for (int m_ = 0; m_ < 4; ++m_) {                                          \
        Ah_[m_] = *(const f16x8*)&bp_[aoffH[m_]];                             \
        Al_[m_] = *(const f16x8*)&bp_[aoffL[m_]];                             \
    }                                                                         \
    _Pragma("unroll")                                                         \
    for (int n_ = 0; n_ < 4; ++n_) {                                          \
        Bh_[n_] = *(const f16x8*)&bp_[boffH[n_]];                             \
        Bl_[n_] = *(const f16x8*)&bp_[boffL[n_]];                             \
    }                                                                         \
    _Pragma("unroll")                                                         \
    for (int m_ = 0; m_ < 4; ++m_)                                            \
        _Pragma("unroll")                                                     \
        for (int n_ = 0; n_ < 4; ++n_)                                        \
            acc[m_][n_] = __builtin_amdgcn_mfma_f32_16x16x32_f16(Ah_[m_], Bh_[n_], acc[m_][n_], 0, 0, 0); \
    _Pragma("unroll")                                                         \
    for (int m_ = 0; m_ < 4; ++m_)                                            \
        _Pragma("unroll")                                                     \
        for (int n_ = 0; n_ < 4; ++n_)                                        \
            acc[m_][n_] = __builtin_amdgcn_mfma_f32_16x16x32_f16(Ah_[m_], Bl_[n_], acc[m_][n_], 0, 0, 0); \
    _Pragma("unroll")                                                         \
    for (int m_ = 0; m_ < 4; ++m_)                                            \
        _Pragma("unroll")                                                     \
        for (int n_ = 0; n_ < 4; ++n_)                                        \
            acc[m_][n_] = __builtin_amdgcn_mfma_f32_16x16x32_f16(Al_[m_], Bh_[n_], acc[m_][n_], 0, 0, 0); \
} while (0)

// One pipeline iteration; RLOAD receives B(KT+1), RCONV holds B(KT).
#define ITER(KT, RLOAD, RCONV, VMC, DOA, DOB, DOCV) do {                      \
    __builtin_amdgcn_s_barrier();   /* all waves done with prior compute */   \
    {                                                                         \
        const int qn_ = ((((KT) + 1) & 1) << 15);                             \
        const int qc_ = (((KT) & 1) << 15);                                   \
        if (DOA) STAGE_A((KT) + 1, qn_);                                      \
        if (DOB) LOAD_B((KT) + 1, RLOAD);                                     \
        asm volatile("s_waitcnt vmcnt(" #VMC ")" ::: "memory");               \
        if (DOCV) {                                                           \
            CONV_WRITE(qc_, RCONV);                                           \
            asm volatile("s_waitcnt lgkmcnt(0)" ::: "memory");                \
        }                                                                     \
        __builtin_amdgcn_s_barrier();  /* tile KT fully resident */           \
        __builtin_amdgcn_sched_barrier(0);                                    \
        COMPUTE(qc_);                                                         \
    }                                                                         \
} while (0)

    B4 sB0, sB1;
    // prologue: A(0)->buf0, B(0)->sB1, drain, convert B(0) into buf0
    STAGE_A(0, 0);
    LOAD_B(0, sB1);
    asm volatile("s_waitcnt vmcnt(0)" ::: "memory");
    CONV_WRITE(0, sB1);
    asm volatile("s_waitcnt lgkmcnt(0)" ::: "memory");
    // invariant entering iter kt (kt>=1): outstanding = A(kt)x4 + B(kt)x4 = 8

    ITER(0, sB0, sB1, 8, 1, 1, 0);          // load B(1)->sB0; B(0) pre-written
    for (int m = 0; m < 15; ++m) {
        ITER(2 * m + 1, sB1, sB0, 8, 1, 1, 1);   // load B(2m+2), conv B(2m+1)
        ITER(2 * m + 2, sB0, sB1, 8, 1, 1, 1);   // load B(2m+3), conv B(2m+2)
    }
    ITER(31, sB1, sB0, 0, 0, 0, 1);         // conv B(31); drain; last compute

    // epilogue: C[t'][n][b]; C/D map col=lane&15, row=(lane>>4)*4+j
    float* cp = C + (size_t)(wg >> 3) * NB;
    const int rg = (lane >> 4) << 2;
    #pragma unroll
    for (int m = 0; m < 4; ++m) {
        int nrow = n0 + wr + m * 16 + rg;
        #pragma unroll
        for (int n = 0; n < 4; ++n) {
            int col = wc + n * 16 + l15;
            #pragma unroll
            for (int j = 0; j < 4; ++j)
                cp[(size_t)(nrow + j) * B_DIM + col] = acc[m][n][j];
        }
    }
}

// -------------------------------------------------------------------------
// Sequential LIF scan per (n,b); state carried across chunk launches.
// -------------------------------------------------------------------------
__global__ __launch_bounds__(256) void spk_scan_kernel(
    const float* __restrict__ cur,   // [tc, NB]
    float* __restrict__ mp_state,    // [NB]
    float* __restrict__ out,         // [NB]
    int tc, int first)
{
    const int nb = blockIdx.x * 256 + threadIdx.x;
    float mp, cnt;
    if (first) { mp = 0.0f; cnt = 0.0f; }
    else       { mp = mp_state[nb]; cnt = out[nb]; }

    const float* p = cur + nb;
    #pragma unroll 8
    for (int t = 0; t < tc; ++t) {
        float c = p[(size_t)t * NB];
        mp = __fadd_rn(__fmul_rn(DECAY, mp), c);
        if (mp >= THRESH) { cnt += 1.0f; mp = 0.0f; }
    }
    mp_state[nb] = mp;
    out[nb] = cnt;
}

extern "C" void kernel_launch(void* const* d_in, const int* in_sizes, int n_in,
                              void* d_out, int out_size, void* d_ws, size_t ws_size,
                              hipStream_t stream) {
    const float* x = (const float*)d_in[0];   // [B, T, I]
    const float* w = (const float*)d_in[1];   // [N, I]
    float* out = (float*)d_out;               // [N, B]

    uint8_t* ws = (uint8_t*)d_ws;
    float* mp  = (float*)ws;                                 // 512 KB
    f16*   Wsp = (f16*)(ws + 524288);                        // 4 MB combined W
    uint8_t* rest = ws + 524288 + 4194304;
    size_t rem = ws_size - 524288 - 4194304;

    // per-t footprint: cur only (512 KB)
    int Tc = (int)(rem / (size_t)(NB * 4));
    if (Tc > T_DIM) Tc = T_DIM;
    if (Tc < 1) Tc = 1;

    float* cur = (float*)rest;                               // Tc * 512 KB

    split_w_kernel<<<(N_DIM * I_DIM / 8) / 256, 256, 0, stream>>>(w, Wsp);

    int first = 1;
    for (int t0 = 0; t0 < T_DIM; ) {
        int tc = T_DIM - t0;
        if (tc > Tc) tc = Tc;

        spk_gemm_kernel<<<tc * 8, 256, 0, stream>>>((const uint8_t*)Wsp, x, cur, t0);
        spk_scan_kernel<<<NB / 256, 256, 0, stream>>>(cur, mp, out, tc, first);

        first = 0;
        t0 += tc;
    }
}

// Round 8
// 565.014 us; speedup vs baseline: 1.2099x; 1.0326x over previous
//
#include <hip/hip_runtime.h>
#include <stdint.h>

#define T_DIM 512
#define B_DIM 128
#define I_DIM 1024
#define N_DIM 1024
#define NB (N_DIM * B_DIM)     // 131072
#define ROWB 4096              // bytes per combined row: I * (hi+lo f16) = 4 KB

#define DECAY 0.9f
#define THRESH 1.0f

typedef _Float16 f16;
typedef _Float16 f16x8 __attribute__((ext_vector_type(8)));
typedef float f32x16 __attribute__((ext_vector_type(16)));

// -------------------------------------------------------------------------
// Split fp32 -> combined f16 hi/lo layout: dst[row][kc=0..127][hl][8 f16].
// -------------------------------------------------------------------------
__global__ __launch_bounds__(256) void split_w_kernel(
    const float* __restrict__ W, f16* __restrict__ Ws)
{
    int gid = blockIdx.x * 256 + threadIdx.x;       // N*I/8 kchunks
    int kc  = gid & 127;
    int row = gid >> 7;
    const float* src = W + (size_t)row * I_DIM + kc * 8;
    f16* dst = Ws + (size_t)row * 2048 + kc * 16;
    float v[8];
    *(float4*)&v[0] = *(const float4*)src;
    *(float4*)&v[4] = *(const float4*)(src + 4);
    f16 hi[8], lo[8];
    #pragma unroll
    for (int j = 0; j < 8; ++j) {
        hi[j] = (f16)v[j];
        lo[j] = (f16)(v[j] - (float)hi[j]);
    }
    *(f16x8*)dst       = *(const f16x8*)hi;
    *(f16x8*)(dst + 8) = *(const f16x8*)lo;
}

// X chunk: rows indexed [t'][b] (t-major)
__global__ __launch_bounds__(256) void split_x_kernel(
    const float* __restrict__ X, f16* __restrict__ Xc, int t0)
{
    int gid = blockIdx.x * 256 + threadIdx.x;       // tc*128*128 kchunks
    int kc = gid & 127;
    int b  = (gid >> 7) & 127;
    int tp = gid >> 14;
    const float* src = X + ((size_t)b * T_DIM + (t0 + tp)) * I_DIM + kc * 8;
    f16* dst = Xc + ((size_t)tp * 128 + b) * 2048 + kc * 16;
    float v[8];
    *(float4*)&v[0] = *(const float4*)src;
    *(float4*)&v[4] = *(const float4*)(src + 4);
    f16 hi[8], lo[8];
    #pragma unroll
    for (int j = 0; j < 8; ++j) {
        hi[j] = (f16)v[j];
        lo[j] = (f16)(v[j] - (float)hi[j]);
    }
    *(f16x8*)dst       = *(const f16x8*)hi;
    *(f16x8*)(dst + 8) = *(const f16x8*)lo;
}

// -------------------------------------------------------------------------
// GEMM via fp16-split 3xMFMA using 32x32x16 (2382 vs 2075 TF ceiling).
// Round-3 structure verbatim otherwise: 128n x 128b tile / block / t,
// 4 waves (64x64 each), BK=32, 2 x 32KB LDS dbuf, 2 blocks/CU,
// ONE __syncthreads per K-step, stage of tile kt+1 in flight across
// the whole compute phase of tile kt.
// Wave tile = 2x2 fragments of 32x32; per K32: 16 ds_read_b128, 24 MFMA.
// -------------------------------------------------------------------------
__global__ __launch_bounds__(256, 2) void spk_gemm_kernel(
    const uint8_t* __restrict__ Wsb,   // combined W  [N][kc][hl][8]
    const uint8_t* __restrict__ Xcb,   // combined Xc [t'*128+b][kc][hl][8]
    float* __restrict__ C, int tc)
{
    __shared__ __align__(16) uint8_t lds[65536];   // 2 x (A 16K | B 16K)

    const int tid  = threadIdx.x;
    const int wave = tid >> 6, lane = tid & 63;

    // bijective chunked XCD swizzle: same-t blocks colocate on one XCD
    const int nwg = gridDim.x;
    const int q = nwg >> 3, r = nwg & 7;
    const int xcd = blockIdx.x & 7, idx = blockIdx.x >> 3;
    const int wg = (xcd < r ? xcd * (q + 1) : r * (q + 1) + (xcd - r) * q) + idx;
    const int n0 = (wg & 7) << 7;
    const int tp = wg >> 3;

    // staging: 8 granules (16B) per thread; LDS dest linear (granule G*16),
    // source granule XOR-swizzled within each 128B row-chunk.
    const uint8_t* srcp[8];
    #pragma unroll
    for (int c = 0; c < 8; ++c) {
        int Gall = (wave * 8 + c) * 64 + lane;
        int G  = Gall & 1023;
        int rr = G >> 3, gg = G & 7;
        int xofs = ((gg ^ (rr & 7)) << 4);
        if (Gall < 1024)
            srcp[c] = Wsb + (size_t)(n0 + rr) * ROWB + xofs;
        else
            srcp[c] = Xcb + ((size_t)tp * 128 + rr) * ROWB + xofs;
    }

    // fragment offsets: 32x32x16 layout — row/col = lane&31, k-octet = lane>>5
    const int wr = ((wave >> 1) << 6);   // n-offset 0/64
    const int wc = ((wave & 1) << 6);    // b-offset 0/64
    const int l31 = lane & 31, ko = lane >> 5;
    int aoff[2][2][2], boff[2][2][2];    // [m][kh][hl]
    #pragma unroll
    for (int m = 0; m < 2; ++m)
        #pragma unroll
        for (int kh = 0; kh < 2; ++kh)
            #pragma unroll
            for (int hl = 0; hl < 2; ++hl) {
                int g  = 4 * kh + 2 * ko + hl;     // granule within 128B tile-row
                int ra = wr + m * 32 + l31;
                aoff[m][kh][hl] = ra * 128 + ((g ^ (ra & 7)) << 4);
                int rb = wc + m * 32 + l31;
                boff[m][kh][hl] = 16384 + rb * 128 + ((g ^ (rb & 7)) << 4);
            }

    f32x16 acc[2][2];
    #pragma unroll
    for (int m = 0; m < 2; ++m)
        #pragma unroll
        for (int n = 0; n < 2; ++n)
            #pragma unroll
            for (int j = 0; j < 16; ++j) acc[m][n][j] = 0.0f;

    // prologue: stage tile 0 into buffer 0
    #pragma unroll
    for (int c = 0; c < 8; ++c)
        __builtin_amdgcn_global_load_lds(
            (const __attribute__((address_space(1))) uint8_t*)srcp[c],
            (__attribute__((address_space(3))) uint8_t*)&lds[(wave * 8 + c) << 10],
            16, 0, 0);

    int cur = 0;
    for (int ks = 0; ks < 32; ++ks) {
        __syncthreads();   // drains vmcnt(0): buf[cur] ready; WAR-safe for stage below

        // stage NEXT K-step into the other buffer (in flight across the MFMAs)
        if (ks + 1 < 32) {
            const int nb = (cur ^ 1) << 15;
            #pragma unroll
            for (int c = 0; c < 8; ++c)
                __builtin_amdgcn_global_load_lds(
                    (const __attribute__((address_space(1))) uint8_t*)(srcp[c] + (ks + 1) * 128),
                    (__attribute__((address_space(3))) uint8_t*)&lds[nb + ((wave * 8 + c) << 10)],
                    16, 0, 0);
        }

        const uint8_t* bp = &lds[cur << 15];
        #pragma unroll
        for (int kh = 0; kh < 2; ++kh) {
            f16x8 Ah[2], Al[2], Bh[2], Bl[2];
            #pragma unroll
            for (int m = 0; m < 2; ++m) {
                Ah[m] = *(const f16x8*)&bp[aoff[m][kh][0]];
                Al[m] = *(const f16x8*)&bp[aoff[m][kh][1]];
                Bh[m] = *(const f16x8*)&bp[boff[m][kh][0]];
                Bl[m] = *(const f16x8*)&bp[boff[m][kh][1]];
            }
            // 12 MFMA term-outer: 4 independent ops between acc reuses
            #pragma unroll
            for (int m = 0; m < 2; ++m)
                #pragma unroll
                for (int n = 0; n < 2; ++n)
                    acc[m][n] = __builtin_amdgcn_mfma_f32_32x32x16_f16(Ah[m], Bh[n], acc[m][n], 0, 0, 0);
            #pragma unroll
            for (int m = 0; m < 2; ++m)
                #pragma unroll
                for (int n = 0; n < 2; ++n)
                    acc[m][n] = __builtin_amdgcn_mfma_f32_32x32x16_f16(Ah[m], Bl[n], acc[m][n], 0, 0, 0);
            #pragma unroll
            for (int m = 0; m < 2; ++m)
                #pragma unroll
                for (int n = 0; n < 2; ++n)
                    acc[m][n] = __builtin_amdgcn_mfma_f32_32x32x16_f16(Al[m], Bh[n], acc[m][n], 0, 0, 0);
        }
        cur ^= 1;
    }

    // epilogue: C[t'][n][b]
    // 32x32 C/D map: col = lane&31, row = (reg&3) + 8*(reg>>2) + 4*(lane>>5)
    float* cp = C + (size_t)tp * NB;
    #pragma unroll
    for (int m = 0; m < 2; ++m) {
        #pragma unroll
        for (int n = 0; n < 2; ++n) {
            int col = wc + n * 32 + l31;
            #pragma unroll
            for (int reg = 0; reg < 16; ++reg) {
                int row = n0 + wr + m * 32 + (reg & 3) + 8 * (reg >> 2) + 4 * ko;
                cp[(size_t)row * B_DIM + col] = acc[m][n][reg];
            }
        }
    }
}

// -------------------------------------------------------------------------
// Sequential LIF scan per (n,b); state carried across chunk launches.
// -------------------------------------------------------------------------
__global__ __launch_bounds__(256) void spk_scan_kernel(
    const float* __restrict__ cur,   // [tc, NB]
    float* __restrict__ mp_state,    // [NB]
    float* __restrict__ out,         // [NB]
    int tc, int first)
{
    const int nb = blockIdx.x * 256 + threadIdx.x;
    float mp, cnt;
    if (first) { mp = 0.0f; cnt = 0.0f; }
    else       { mp = mp_state[nb]; cnt = out[nb]; }

    const float* p = cur + nb;
    #pragma unroll 8
    for (int t = 0; t < tc; ++t) {
        float c = p[(size_t)t * NB];
        mp = __fadd_rn(__fmul_rn(DECAY, mp), c);
        if (mp >= THRESH) { cnt += 1.0f; mp = 0.0f; }
    }
    mp_state[nb] = mp;
    out[nb] = cnt;
}

extern "C" void kernel_launch(void* const* d_in, const int* in_sizes, int n_in,
                              void* d_out, int out_size, void* d_ws, size_t ws_size,
                              hipStream_t stream) {
    const float* x = (const float*)d_in[0];   // [B, T, I]
    const float* w = (const float*)d_in[1];   // [N, I]
    float* out = (float*)d_out;               // [N, B]

    uint8_t* ws = (uint8_t*)d_ws;
    float* mp  = (float*)ws;                                 // 512 KB
    f16*   Wsp = (f16*)(ws + 524288);                        // 4 MB combined W
    uint8_t* rest = ws + 524288 + 4194304;
    size_t rem = ws_size - 524288 - 4194304;

    // per-t footprint: Xc row block 512KB + cur 512KB = 1 MB
    int Tc = (int)(rem / (size_t)(128 * ROWB + NB * 4));
    if (Tc > T_DIM) Tc = T_DIM;
    if (Tc < 1) Tc = 1;

    f16*   Xcp = (f16*)rest;                                 // Tc * 512 KB
    float* cur = (float*)(rest + (size_t)Tc * 128 * ROWB);   // Tc * 512 KB

    split_w_kernel<<<(N_DIM * I_DIM / 8) / 256, 256, 0, stream>>>(w, Wsp);

    int first = 1;
    for (int t0 = 0; t0 < T_DIM; ) {
        int tc = T_DIM - t0;
        if (tc > Tc) tc = Tc;

        split_x_kernel<<<tc * 64, 256, 0, stream>>>(x, Xcp, t0);
        spk_gemm_kernel<<<tc * 8, 256, 0, stream>>>(
            (const uint8_t*)Wsp, (const uint8_t*)Xcp, cur, tc);
        spk_scan_kernel<<<NB / 256, 256, 0, stream>>>(cur, mp, out, tc, first);

        first = 0;
        t0 += tc;
    }
}